// Round 2
// baseline (242.332 us; speedup 1.0000x reference)
//
#include <hip/hip_runtime.h>
#include <hip/hip_bf16.h>
#include <cstdint>
#include <cstddef>

// Problem constants
#define B_  8192
#define D_  256
#define H_  512
#define K_  1280   // D + 2H
#define N_  2560   // 5H
#define NT_ 320    // N-tile: 2 h-groups of (32 h x 5 gates)

typedef short short8  __attribute__((ext_vector_type(8)));
typedef float f32x4   __attribute__((ext_vector_type(4)));
typedef float f32x16  __attribute__((ext_vector_type(16)));

__device__ __forceinline__ float sigf(float x)     { return 1.f / (1.f + __expf(-x)); }
__device__ __forceinline__ float tanhfast(float x) { return 1.f - 2.f / (__expf(2.f * x) + 1.f); }

// ---------------------------------------------------------------------------
// prep, SPLIT into two kernels this round so rocprof attributes their cost
// separately (total-vs-dispatch gap diagnosis).
// prep_a: pack [x | h_t | h_s] -> bf16 A[B_, K_], 8 elem/thr.  5120 blocks.
// prep_w: bf16 WT[n',k], n' = (h>>5)*160 + g*32 + (h&31).      800 blocks.
// ---------------------------------------------------------------------------
struct WPtrs {
    const float* U[5];
    const float* Wt[5];
    const float* Ws[5];
};

__global__ void prep_a_kernel(const float* __restrict__ x, const float* __restrict__ ht,
                              const float* __restrict__ hs, __hip_bfloat16* __restrict__ A) {
    int t = blockIdx.x * 256 + threadIdx.x;   // over B_*K_/8
    int idx8 = t * 8;
    int b = idx8 / K_;
    int k = idx8 - b * K_;
    const float* src;
    if (k < D_)            src = x  + (size_t)b * D_ + k;
    else if (k < D_ + H_)  src = ht + (size_t)b * H_ + (k - D_);
    else                   src = hs + (size_t)b * H_ + (k - D_ - H_);
    f32x4 v0 = *(const f32x4*)(src);
    f32x4 v1 = *(const f32x4*)(src + 4);
    union { short8 s; __hip_bfloat16 h[8]; } o;
    o.h[0] = __float2bfloat16(v0[0]); o.h[1] = __float2bfloat16(v0[1]);
    o.h[2] = __float2bfloat16(v0[2]); o.h[3] = __float2bfloat16(v0[3]);
    o.h[4] = __float2bfloat16(v1[0]); o.h[5] = __float2bfloat16(v1[1]);
    o.h[6] = __float2bfloat16(v1[2]); o.h[7] = __float2bfloat16(v1[3]);
    *(short8*)(A + idx8) = o.s;
}

__global__ void prep_w_kernel(WPtrs p, __hip_bfloat16* __restrict__ WT) {
    // 66-short row pitch: read tile[th][hl] puts lane th at byte th*132 ->
    // bank (33*th + hl>>1) & 31 -> 2 lanes/bank (free).
    __shared__ __hip_bfloat16 tile[64][66];
    int bid2 = blockIdx.x;                 // hblk + 8*(kblk + 20*g)
    int hblk = bid2 & 7;
    int kblk = (bid2 >> 3) % 20;
    int g    = bid2 / 160;
    int k0 = kblk * 64;
    int h0 = hblk * 64;
    const float* src; int kl0;
    if (k0 < 256)      { src = p.U[g];  kl0 = k0; }
    else if (k0 < 768) { src = p.Wt[g]; kl0 = k0 - 256; }
    else               { src = p.Ws[g]; kl0 = k0 - 768; }
    int tid = threadIdx.x;
    int tk = tid >> 6;    // 0..3
    int th = tid & 63;
    for (int r = 0; r < 16; ++r) {
        int kl = r * 4 + tk;
        tile[kl][th] = __float2bfloat16(src[(size_t)(kl0 + kl) * H_ + h0 + th]);
    }
    __syncthreads();
    for (int r = 0; r < 16; ++r) {
        int hl = r * 4 + tk;           // h within tile
        int h  = h0 + hl;
        int np = (h >> 5) * 160 + g * 32 + (h & 31);
        WT[(size_t)np * K_ + k0 + th] = tile[th][hl];
    }
}

// ---------------------------------------------------------------------------
// Fused GEMM + LSTM epilogue, 32x32x16 MFMA.
// Block tile 128x320 (= 64 h x 5 gates), 4 waves = 2(m) x 2(n); wave tile
// 64x160 = 2 m-frags x 5 n-frags (one gate each), acc = 160 regs/lane.
// LDS layout: [row][32 k] with k-chunk (16B) XOR-swizzled by (row>>1)&3.
//
// T4 COUNTED-VMCNT pipeline (raw barriers, vmcnt never 0 in main loop):
//   prologue: STAGE(t0->buf0); STAGE(t1->buf1); vmcnt(7); barrier
//   iter t:   14x ds_read_b128(buf[cur]); lgkmcnt(0); sched_barrier(0);
//             setprio(1); 20x MFMA; setprio(0);
//             barrier                       // everyone done READING buf[cur]
//             STAGE(t+2 -> buf[cur]); vmcnt(7)   // waits only tile t+1
//             barrier                       // tile t+1 visible to all waves
// Round-1 post-mortem: __syncthreads() always emits vmcnt(0) -> the per-iter
// drain exposed full load latency regardless of issue point. This is the
// documented fix (m218: counted-vs-drain0 = +38-73%).
// ---------------------------------------------------------------------------
#define GLD16(gp, lp)                                                              \
    __builtin_amdgcn_global_load_lds(                                              \
        (const __attribute__((address_space(1))) unsigned int*)(gp),               \
        (__attribute__((address_space(3))) unsigned int*)(lp), 16, 0, 0)

__global__ __launch_bounds__(256, 2) void gemm_fused_kernel(
    const __hip_bfloat16* __restrict__ A, const __hip_bfloat16* __restrict__ WT,
    const float* __restrict__ ct, const float* __restrict__ cs,
    const float* __restrict__ bi, const float* __restrict__ bfs,
    const float* __restrict__ bft, const float* __restrict__ bo,
    const float* __restrict__ bc, float* __restrict__ out) {
    __shared__ alignas(16) unsigned short sA[2][128 * 32];  // 16 KB
    __shared__ alignas(16) unsigned short sB[2][NT_ * 32];  // 40 KB

    int tid = threadIdx.x;
    int m0 = blockIdx.x * 128;   // row tile (fast axis -> W col-tile L2-hot per XCD)
    int n0 = blockIdx.y * NT_;   // W column tile (slow axis)
    int wid  = tid >> 6, lane = tid & 63;
    int wm   = wid >> 1;         // 0..1: 64-row slice
    int wn   = wid & 1;          // 0..1: 160-col (32-h-group) slice
    int half = lane >> 5, l31 = lane & 31;

    int hg = blockIdx.y * 2 + wn;      // 32-h group
    int h  = hg * 32 + l31;            // this lane's h column
    float Bi = bi[h], Bfs = bfs[h], Bft = bft[h], Bo = bo[h], Bc = bc[h];

    f32x16 acc[2][5];
#pragma unroll
    for (int i = 0; i < 2; ++i)
#pragma unroll
        for (int j = 0; j < 5; ++j)
            acc[i][j] = (f32x16)(0.f);

    // Staging: chunk c -> LDS bytes [c*16, c*16+16); row = c>>2, chunk pos = c&3.
    // Global k-chunk loaded = pos ^ ((row>>1)&3)  (bank swizzle, bijective per row).
    const __hip_bfloat16* aSrc[2]; int aOff[2];
#pragma unroll
    for (int i = 0; i < 2; ++i) {
        int c = tid + 256 * i;
        int row = c >> 2, pos = c & 3;
        int kc = pos ^ ((row >> 1) & 3);
        aSrc[i] = A + (size_t)(m0 + row) * K_ + kc * 8;
        aOff[i] = c * 8;
    }
    const __hip_bfloat16* bSrc[5]; int bOff[5];
#pragma unroll
    for (int i = 0; i < 5; ++i) {
        int c = tid + 256 * i;
        int row = c >> 2, pos = c & 3;
        int kc = pos ^ ((row >> 1) & 3);
        bSrc[i] = WT + (size_t)(n0 + row) * K_ + kc * 8;
        bOff[i] = c * 8;
    }

#define STAGE(buf, koff)                                                \
    do {                                                                \
        _Pragma("unroll")                                               \
        for (int i_ = 0; i_ < 2; ++i_)                                  \
            GLD16(aSrc[i_] + (koff), &sA[buf][aOff[i_]]);               \
        _Pragma("unroll")                                               \
        for (int i_ = 0; i_ < 5; ++i_)                                  \
            GLD16(bSrc[i_] + (koff), &sB[buf][bOff[i_]]);               \
    } while (0)

    // Frag read offsets (shorts): row*32 + (chunk ^ ((row>>1)&3))*8, chunk = ks*2+half
    int arow[2], brow[5];
#pragma unroll
    for (int i = 0; i < 2; ++i) arow[i] = wm * 64 + i * 32 + l31;
#pragma unroll
    for (int j = 0; j < 5; ++j) brow[j] = wn * 160 + j * 32 + l31;

    // ---- prologue: two tiles in flight ----
    STAGE(0, 0);
    STAGE(1, 32);
    asm volatile("s_waitcnt vmcnt(7)" ::: "memory");   // tile 0 landed; tile 1 in flight
    __builtin_amdgcn_s_barrier();

    const int nt = K_ / 32;   // 40
#pragma unroll 2
    for (int t = 0; t < nt; ++t) {
        int cur = t & 1;
        short8 a[2][2], b[5][2];
#pragma unroll
        for (int ks = 0; ks < 2; ++ks) {
#pragma unroll
            for (int i = 0; i < 2; ++i) {
                int pos = (ks * 2 + half) ^ ((arow[i] >> 1) & 3);
                a[i][ks] = *(const short8*)(&sA[cur][arow[i] * 32 + pos * 8]);
            }
#pragma unroll
            for (int j = 0; j < 5; ++j) {
                int pos = (ks * 2 + half) ^ ((brow[j] >> 1) & 3);
                b[j][ks] = *(const short8*)(&sB[cur][brow[j] * 32 + pos * 8]);
            }
        }
        asm volatile("s_waitcnt lgkmcnt(0)" ::: "memory");
        __builtin_amdgcn_sched_barrier(0);   // rule #18: keep MFMA below the wait
        __builtin_amdgcn_s_setprio(1);
#pragma unroll
        for (int ks = 0; ks < 2; ++ks)
#pragma unroll
            for (int j = 0; j < 5; ++j)
#pragma unroll
                for (int i = 0; i < 2; ++i)
                    acc[i][j] = __builtin_amdgcn_mfma_f32_32x32x16_bf16(a[i][ks], b[j][ks], acc[i][j], 0, 0, 0);
        __builtin_amdgcn_s_setprio(0);

        __builtin_amdgcn_s_barrier();        // all waves done reading buf[cur]
        if (t + 2 < nt) {
            STAGE(cur, (t + 2) * 32);        // overwrite freed buffer
            asm volatile("s_waitcnt vmcnt(7)" ::: "memory");  // tile t+1 landed
        } else {
            asm volatile("s_waitcnt vmcnt(0)" ::: "memory");  // tail drain (cheap)
        }
        __builtin_amdgcn_s_barrier();        // tile t+1 visible to all waves
    }

    // Lane-local LSTM epilogue.
    // 32x32 C/D layout: col = lane&31 (h), row = (r&3) + 8*(r>>2) + 4*half.
#pragma unroll
    for (int i = 0; i < 2; ++i) {
        int rbase = m0 + wm * 64 + i * 32 + 4 * half;
#pragma unroll
        for (int r = 0; r < 16; ++r) {
            int row = rbase + (r & 3) + 8 * (r >> 2);
            size_t idx = (size_t)row * H_ + h;
            float i_n  = sigf(acc[i][0][r] + Bi);
            float fs_n = sigf(acc[i][1][r] + Bfs);
            float ft_n = sigf(acc[i][2][r] + Bft);
            float o_n  = sigf(acc[i][3][r] + Bo);
            float c_n  = tanhfast(acc[i][4][r] + Bc);
            float ch   = i_n * c_n + ft_n * ct[idx] + fs_n * cs[idx];
            out[idx] = o_n * tanhfast(ch);
            out[(size_t)B_ * H_ + idx] = ch;
        }
    }
#undef STAGE
}

// ---------------------------------------------------------------------------
// Fallback (ws too small): one block per row, fp32 direct. Slow but correct.
// ---------------------------------------------------------------------------
struct AllW {
    const float* U[5];
    const float* Wt[5];
    const float* Ws[5];
    const float* bias[5];
};

__global__ __launch_bounds__(512) void fallback_kernel(const float* __restrict__ x,
                                                       const float* __restrict__ ht,
                                                       const float* __restrict__ hs,
                                                       const float* __restrict__ ct,
                                                       const float* __restrict__ cs,
                                                       AllW w, float* __restrict__ out) {
    __shared__ float arow[K_];
    int b = blockIdx.x;
    int h = threadIdx.x;
    for (int k = h; k < K_; k += 512) {
        float v;
        if (k < D_)           v = x[b * D_ + k];
        else if (k < D_ + H_) v = ht[b * H_ + k - D_];
        else                  v = hs[b * H_ + k - D_ - H_];
        arow[k] = v;
    }
    __syncthreads();
    float g[5];
    for (int gi = 0; gi < 5; ++gi) {
        float s = w.bias[gi][h];
        const float* U = w.U[gi];
        for (int k = 0; k < D_; ++k) s += arow[k] * U[(size_t)k * H_ + h];
        const float* Wt = w.Wt[gi];
        for (int k = 0; k < H_; ++k) s += arow[D_ + k] * Wt[(size_t)k * H_ + h];
        const float* Ws = w.Ws[gi];
        for (int k = 0; k < H_; ++k) s += arow[D_ + H_ + k] * Ws[(size_t)k * H_ + h];
        g[gi] = s;
    }
    int idx = b * H_ + h;
    float i_n = sigf(g[0]), fs_n = sigf(g[1]), ft_n = sigf(g[2]), o_n = sigf(g[3]);
    float c_n = tanhfast(g[4]);
    float ch  = i_n * c_n + ft_n * ct[idx] + fs_n * cs[idx];
    out[idx] = o_n * tanhfast(ch);
    out[(size_t)B_ * H_ + idx] = ch;
}

// ---------------------------------------------------------------------------
extern "C" void kernel_launch(void* const* d_in, const int* in_sizes, int n_in,
                              void* d_out, int out_size, void* d_ws, size_t ws_size,
                              hipStream_t stream) {
    const float* x  = (const float*)d_in[0];
    const float* ht = (const float*)d_in[1];
    const float* hs = (const float*)d_in[2];
    const float* ct = (const float*)d_in[3];
    const float* cs = (const float*)d_in[4];

    WPtrs wp;
    AllW  aw;
    const float* bias[5];
    for (int g = 0; g < 5; ++g) {
        wp.U[g]  = (const float*)d_in[5 + g * 4 + 0];
        wp.Wt[g] = (const float*)d_in[5 + g * 4 + 1];
        wp.Ws[g] = (const float*)d_in[5 + g * 4 + 2];
        bias[g]  = (const float*)d_in[5 + g * 4 + 3];
        aw.U[g] = wp.U[g]; aw.Wt[g] = wp.Wt[g]; aw.Ws[g] = wp.Ws[g]; aw.bias[g] = bias[g];
    }
    float* out = (float*)d_out;

    size_t szA = (size_t)B_ * K_ * 2;  // 20 MB
    size_t szW = (size_t)N_ * K_ * 2;  // 6.25 MB

    if (ws_size >= szA + szW) {
        __hip_bfloat16* Abf = (__hip_bfloat16*)d_ws;
        __hip_bfloat16* WT  = (__hip_bfloat16*)((char*)d_ws + szA);

        prep_a_kernel<<<5120, 256, 0, stream>>>(x, ht, hs, Abf);
        prep_w_kernel<<<800, 256, 0, stream>>>(wp, WT);
        gemm_fused_kernel<<<dim3(B_ / 128, N_ / NT_), 256, 0, stream>>>(
            Abf, WT, ct, cs, bias[0], bias[1], bias[2], bias[3], bias[4], out);
    } else {
        fallback_kernel<<<B_, 512, 0, stream>>>(x, ht, hs, ct, cs, aw, out);
    }
}

// Round 3
// 234.538 us; speedup vs baseline: 1.0332x; 1.0332x over previous
//
#include <hip/hip_runtime.h>
#include <hip/hip_bf16.h>
#include <cstdint>
#include <cstddef>

// Problem constants
#define B_  8192
#define D_  256
#define H_  512
#define K_  1280   // D + 2H
#define N_  2560   // 5H
#define NT_ 320    // N-tile: 2 h-groups of (32 h x 5 gates)
#define BM_ 256    // M-tile
#define BK_ 64     // K-step

typedef short short8  __attribute__((ext_vector_type(8)));
typedef float f32x4   __attribute__((ext_vector_type(4)));
typedef float f32x16  __attribute__((ext_vector_type(16)));

__device__ __forceinline__ float sigf(float x)     { return 1.f / (1.f + __expf(-x)); }
__device__ __forceinline__ float tanhfast(float x) { return 1.f - 2.f / (__expf(2.f * x) + 1.f); }

// ---------------------------------------------------------------------------
// prep kernels (split so rocprof attributes their cost separately).
// prep_a: pack [x | h_t | h_s] -> bf16 A[B_, K_], 8 elem/thr.  5120 blocks.
// prep_w: bf16 WT[n',k], n' = (h>>5)*160 + g*32 + (h&31).      800 blocks.
// ---------------------------------------------------------------------------
struct WPtrs {
    const float* U[5];
    const float* Wt[5];
    const float* Ws[5];
};

__global__ void prep_a_kernel(const float* __restrict__ x, const float* __restrict__ ht,
                              const float* __restrict__ hs, __hip_bfloat16* __restrict__ A) {
    int t = blockIdx.x * 256 + threadIdx.x;   // over B_*K_/8
    int idx8 = t * 8;
    int b = idx8 / K_;
    int k = idx8 - b * K_;
    const float* src;
    if (k < D_)            src = x  + (size_t)b * D_ + k;
    else if (k < D_ + H_)  src = ht + (size_t)b * H_ + (k - D_);
    else                   src = hs + (size_t)b * H_ + (k - D_ - H_);
    f32x4 v0 = *(const f32x4*)(src);
    f32x4 v1 = *(const f32x4*)(src + 4);
    union { short8 s; __hip_bfloat16 h[8]; } o;
    o.h[0] = __float2bfloat16(v0[0]); o.h[1] = __float2bfloat16(v0[1]);
    o.h[2] = __float2bfloat16(v0[2]); o.h[3] = __float2bfloat16(v0[3]);
    o.h[4] = __float2bfloat16(v1[0]); o.h[5] = __float2bfloat16(v1[1]);
    o.h[6] = __float2bfloat16(v1[2]); o.h[7] = __float2bfloat16(v1[3]);
    *(short8*)(A + idx8) = o.s;
}

__global__ void prep_w_kernel(WPtrs p, __hip_bfloat16* __restrict__ WT) {
    __shared__ __hip_bfloat16 tile[64][66];   // 66-pitch: 2-way (free) on read
    int bid2 = blockIdx.x;                 // hblk + 8*(kblk + 20*g)
    int hblk = bid2 & 7;
    int kblk = (bid2 >> 3) % 20;
    int g    = bid2 / 160;
    int k0 = kblk * 64;
    int h0 = hblk * 64;
    const float* src; int kl0;
    if (k0 < 256)      { src = p.U[g];  kl0 = k0; }
    else if (k0 < 768) { src = p.Wt[g]; kl0 = k0 - 256; }
    else               { src = p.Ws[g]; kl0 = k0 - 768; }
    int tid = threadIdx.x;
    int tk = tid >> 6;    // 0..3
    int th = tid & 63;
    for (int r = 0; r < 16; ++r) {
        int kl = r * 4 + tk;
        tile[kl][th] = __float2bfloat16(src[(size_t)(kl0 + kl) * H_ + h0 + th]);
    }
    __syncthreads();
    for (int r = 0; r < 16; ++r) {
        int hl = r * 4 + tk;           // h within tile
        int h  = h0 + hl;
        int np = (h >> 5) * 160 + g * 32 + (h & 31);
        WT[(size_t)np * K_ + k0 + th] = tile[th][hl];
    }
}

// ---------------------------------------------------------------------------
// Fused GEMM + LSTM epilogue — 8-wave big-step structure (R2 post-mortem:
// 2-block/CU 20-MFMA phases were stall/barrier-dominated; pipelining tweaks
// all null/negative, matching the documented 2-phase regime gate).
//
// Geometry: grid (8, 32) = 256 blocks = exactly 1/CU (no tail, no 2-block
// barrier interference). Block = 512 thr = 8 waves (wm 0..3 x wn 0..1),
// block tile 256x320, wave tile 64x160 = 2 m-frags x 5 n-frags (32x32x16),
// acc 160 f32/lane. BK=64 -> 80 MFMA per step, ONE __syncthreads per step
// (20 barriers total vs 80 before). Staging for step t+1 is issued at the
// TOP of step t -> in flight ~the whole step, so the barrier's vmcnt(0)
// drain is nearly free (this is what R1/R2's short steps could never give).
//
// LDS: [2 buf][rows][8 chunks of 16B], chunk position pos = chunk^(row&7):
// - ds_read frag (rows stride 128B): banks = pos*4+j, pos spans 0..7 over
//   any 8 consecutive rows -> conflict-free (8-cyc floor).
// - staging (rule #21 both-sides): GLD16 dest LINEAR (t*16B), global source
//   pre-swizzled: thread t loads chunk (t&7)^((t>>3)&7) of row t>>3.
// ---------------------------------------------------------------------------
#define GLD16(gp, lp)                                                              \
    __builtin_amdgcn_global_load_lds(                                              \
        (const __attribute__((address_space(1))) unsigned int*)(gp),               \
        (__attribute__((address_space(3))) unsigned int*)(lp), 16, 0, 0)

__global__ __launch_bounds__(512, 2) void gemm_fused_kernel(
    const __hip_bfloat16* __restrict__ A, const __hip_bfloat16* __restrict__ WT,
    const float* __restrict__ ct, const float* __restrict__ cs,
    const float* __restrict__ bi, const float* __restrict__ bfs,
    const float* __restrict__ bft, const float* __restrict__ bo,
    const float* __restrict__ bc, float* __restrict__ out) {
    __shared__ alignas(16) unsigned short sA[2][BM_ * BK_];  // 64 KB
    __shared__ alignas(16) unsigned short sB[2][NT_ * BK_];  // 80 KB

    int tid = threadIdx.x;
    int n0 = blockIdx.x * NT_;   // fast axis -> one n-tile per XCD (WT L2-hot)
    int m0 = blockIdx.y * BM_;
    int wid  = tid >> 6, lane = tid & 63;
    int wm   = wid >> 1;         // 0..3: 64-row slice
    int wn   = wid & 1;          // 0..1: 160-col (32-h-group x 5 gates) slice
    int half = lane >> 5, l31 = lane & 31;

    int hg = blockIdx.x * 2 + wn;      // 32-h group
    int h  = hg * 32 + l31;            // this lane's h column
    float Bi = bi[h], Bfs = bfs[h], Bft = bft[h], Bo = bo[h], Bc = bc[h];

    f32x16 acc[2][5];
#pragma unroll
    for (int i = 0; i < 2; ++i)
#pragma unroll
        for (int j = 0; j < 5; ++j)
            acc[i][j] = (f32x16)(0.f);

    // ---- staging setup: thread t -> row = t>>3 (+64 per round), LDS pos = t&7,
    // global chunk = (t&7) ^ (row&7) so that LDS[row][pos] holds chunk pos^(row&7).
    int srow = tid >> 3;                       // 0..63
    int cSw  = (tid & 7) ^ (srow & 7);         // pre-swizzled global chunk
    const __hip_bfloat16* aSrcB = A  + (size_t)(m0 + srow) * K_ + cSw * 8;
    const __hip_bfloat16* bSrcB = WT + (size_t)(n0 + srow) * K_ + cSw * 8;
    int t8 = tid * 8;                          // LDS dst in shorts (linear, 16B/lane)

#define STAGE(bufsel, koff)                                                      \
    do {                                                                         \
        _Pragma("unroll")                                                        \
        for (int r_ = 0; r_ < 4; ++r_)                                           \
            GLD16(aSrcB + (size_t)r_ * 64 * K_ + (koff), sA[bufsel] + r_ * 4096 + t8); \
        _Pragma("unroll")                                                        \
        for (int r_ = 0; r_ < 5; ++r_)                                           \
            GLD16(bSrcB + (size_t)r_ * 64 * K_ + (koff), sB[bufsel] + r_ * 4096 + t8); \
    } while (0)

    // ---- fragment read offsets (shorts): row*64 + pos*8, pos = (ks*2+half)^(row&7)
    int arow64[2], brow64[5];
#pragma unroll
    for (int i = 0; i < 2; ++i) arow64[i] = (wm * 64 + i * 32 + l31) * 64;
#pragma unroll
    for (int j = 0; j < 5; ++j) brow64[j] = (wn * 160 + j * 32 + l31) * 64;
    int xr = l31 & 7;
    int pk[4];
#pragma unroll
    for (int ks = 0; ks < 4; ++ks) pk[ks] = ((ks * 2 + half) ^ xr) * 8;

    // ---- prologue: stage step 0 ----
    STAGE(0, 0);
    __syncthreads();   // full drain once (prologue only)

    const int nt = K_ / BK_;   // 20
#pragma unroll 2
    for (int t = 0; t < nt; ++t) {
        int cur = t & 1;
        if (t + 1 < nt) STAGE(cur ^ 1, (t + 1) * BK_);   // in flight all step
        const unsigned short* sAc = sA[cur];
        const unsigned short* sBc = sB[cur];
#pragma unroll
        for (int ks = 0; ks < 4; ++ks) {
            short8 a[2], b[5];
            int po = pk[ks];
#pragma unroll
            for (int i = 0; i < 2; ++i)
                a[i] = *(const short8*)(sAc + arow64[i] + po);
#pragma unroll
            for (int j = 0; j < 5; ++j)
                b[j] = *(const short8*)(sBc + brow64[j] + po);
            __builtin_amdgcn_s_setprio(1);
#pragma unroll
            for (int j = 0; j < 5; ++j)
#pragma unroll
                for (int i = 0; i < 2; ++i)
                    acc[i][j] = __builtin_amdgcn_mfma_f32_32x32x16_bf16(a[i], b[j], acc[i][j], 0, 0, 0);
            __builtin_amdgcn_s_setprio(0);
        }
        // One barrier per 80-MFMA step; its vmcnt(0)/lgkmcnt(0) drain waits on
        // loads issued a full step (~2500 cyc) ago -> nearly free.
        __syncthreads();
    }
#undef STAGE

    // ---- lane-local LSTM epilogue ----
    // 32x32 C/D layout: col = lane&31 (h), row = (r&3) + 8*(r>>2) + 4*half.
#pragma unroll
    for (int i = 0; i < 2; ++i) {
        int rbase = m0 + wm * 64 + i * 32 + 4 * half;
#pragma unroll
        for (int r = 0; r < 16; ++r) {
            int row = rbase + (r & 3) + 8 * (r >> 2);
            size_t idx = (size_t)row * H_ + h;
            float i_n  = sigf(acc[i][0][r] + Bi);
            float fs_n = sigf(acc[i][1][r] + Bfs);
            float ft_n = sigf(acc[i][2][r] + Bft);
            float o_n  = sigf(acc[i][3][r] + Bo);
            float c_n  = tanhfast(acc[i][4][r] + Bc);
            float ch   = i_n * c_n + ft_n * ct[idx] + fs_n * cs[idx];
            out[idx] = o_n * tanhfast(ch);
            out[(size_t)B_ * H_ + idx] = ch;
        }
    }
}

// ---------------------------------------------------------------------------
// Fallback (ws too small): one block per row, fp32 direct. Slow but correct.
// ---------------------------------------------------------------------------
struct AllW {
    const float* U[5];
    const float* Wt[5];
    const float* Ws[5];
    const float* bias[5];
};

__global__ __launch_bounds__(512) void fallback_kernel(const float* __restrict__ x,
                                                       const float* __restrict__ ht,
                                                       const float* __restrict__ hs,
                                                       const float* __restrict__ ct,
                                                       const float* __restrict__ cs,
                                                       AllW w, float* __restrict__ out) {
    __shared__ float arow[K_];
    int b = blockIdx.x;
    int h = threadIdx.x;
    for (int k = h; k < K_; k += 512) {
        float v;
        if (k < D_)           v = x[b * D_ + k];
        else if (k < D_ + H_) v = ht[b * H_ + k - D_];
        else                  v = hs[b * H_ + k - D_ - H_];
        arow[k] = v;
    }
    __syncthreads();
    float g[5];
    for (int gi = 0; gi < 5; ++gi) {
        float s = w.bias[gi][h];
        const float* U = w.U[gi];
        for (int k = 0; k < D_; ++k) s += arow[k] * U[(size_t)k * H_ + h];
        const float* Wt = w.Wt[gi];
        for (int k = 0; k < H_; ++k) s += arow[D_ + k] * Wt[(size_t)k * H_ + h];
        const float* Ws = w.Ws[gi];
        for (int k = 0; k < H_; ++k) s += arow[D_ + H_ + k] * Ws[(size_t)k * H_ + h];
        g[gi] = s;
    }
    int idx = b * H_ + h;
    float i_n = sigf(g[0]), fs_n = sigf(g[1]), ft_n = sigf(g[2]), o_n = sigf(g[3]);
    float c_n = tanhfast(g[4]);
    float ch  = i_n * c_n + ft_n * ct[idx] + fs_n * cs[idx];
    out[idx] = o_n * tanhfast(ch);
    out[(size_t)B_ * H_ + idx] = ch;
}

// ---------------------------------------------------------------------------
extern "C" void kernel_launch(void* const* d_in, const int* in_sizes, int n_in,
                              void* d_out, int out_size, void* d_ws, size_t ws_size,
                              hipStream_t stream) {
    const float* x  = (const float*)d_in[0];
    const float* ht = (const float*)d_in[1];
    const float* hs = (const float*)d_in[2];
    const float* ct = (const float*)d_in[3];
    const float* cs = (const float*)d_in[4];

    WPtrs wp;
    AllW  aw;
    const float* bias[5];
    for (int g = 0; g < 5; ++g) {
        wp.U[g]  = (const float*)d_in[5 + g * 4 + 0];
        wp.Wt[g] = (const float*)d_in[5 + g * 4 + 1];
        wp.Ws[g] = (const float*)d_in[5 + g * 4 + 2];
        bias[g]  = (const float*)d_in[5 + g * 4 + 3];
        aw.U[g] = wp.U[g]; aw.Wt[g] = wp.Wt[g]; aw.Ws[g] = wp.Ws[g]; aw.bias[g] = bias[g];
    }
    float* out = (float*)d_out;

    size_t szA = (size_t)B_ * K_ * 2;  // 20 MB
    size_t szW = (size_t)N_ * K_ * 2;  // 6.25 MB

    if (ws_size >= szA + szW) {
        __hip_bfloat16* Abf = (__hip_bfloat16*)d_ws;
        __hip_bfloat16* WT  = (__hip_bfloat16*)((char*)d_ws + szA);

        prep_a_kernel<<<5120, 256, 0, stream>>>(x, ht, hs, Abf);
        prep_w_kernel<<<800, 256, 0, stream>>>(wp, WT);
        gemm_fused_kernel<<<dim3(N_ / NT_, B_ / BM_), 512, 0, stream>>>(
            Abf, WT, ct, cs, bias[0], bias[1], bias[2], bias[3], bias[4], out);
    } else {
        fallback_kernel<<<B_, 512, 0, stream>>>(x, ht, hs, ct, cs, aw, out);
    }
}